// Round 7
// baseline (3416.837 us; speedup 1.0000x reference)
//
#include <hip/hip_runtime.h>

#define N_NODES 50000
#define N_EDGES 800000
#define NP 50048          // N padded to multiple of 64
#define MAXDEG 64         // CSR slots per node; Poisson(16) -> P(deg>=64) ~ 1e-19
#define PADK 136          // 128 + 8 bf16 pad
#define NCOPY 64          // BN-stat replication
#define EB 3125           // edge blocks (3125*256 == 800000)
#define WPB 512           // wprep blocks appended to k_init grid

typedef __bf16 bf16_8 __attribute__((ext_vector_type(8)));
typedef float  f32_4  __attribute__((ext_vector_type(4)));

__device__ inline float2 bf2f2(unsigned int u) {
    union { unsigned int i; float f; } a, b;
    a.i = u << 16;            // low short  = element 0
    b.i = u & 0xffff0000u;    // high short = element 1
    return make_float2(a.f, b.f);
}

// ---------------- init + weight transpose + svec, one launch ----------------
__global__ void k_init_wprep(int* __restrict__ fillp, float* __restrict__ colpart,
                             float* __restrict__ out_head, int* __restrict__ done,
                             const float* __restrict__ conv_w, const float* __restrict__ lin1_w,
                             __bf16* __restrict__ WT, float* __restrict__ svec) {
    int b = blockIdx.x;
    if (b < EB) {
        int i = b * 256 + threadIdx.x;       // covers exactly N_NODES*16 = 800000
        fillp[i] = 0;
        if (i < 2 * NCOPY * 128) colpart[i] = 0.f;
        if (i < 32) out_head[i] = 0.f;
        if (i == 32) *done = 0;
    } else if (b < EB + WPB) {
        int b2 = b - EB;                     // 0..511
        int mat = b2 >> 7, n = b2 & 127, k = threadIdx.x;
        if (k < 128) {
            const float* srcm = (mat < 3) ? (conv_w + (size_t)mat * 16384) : lin1_w;
            WT[((size_t)mat * 128 + n) * 128 + k] = (__bf16)srcm[(size_t)k * 128 + n];
        }
    } else {
        int j = threadIdx.x;                 // svec = colsum of lin1_w rows 256..511
        if (j < 128) {
            float s = 0.f;
            for (int k = 256; k < 512; ++k) s += lin1_w[(size_t)k * 128 + j];
            svec[j] = s;
        }
    }
}

// ---------------- direct-slot CSR fill: ONE atomic per edge ----------------
__global__ void k_fillover(const int* __restrict__ src, const int* __restrict__ dst,
                           const float* __restrict__ ew,
                           int* __restrict__ fillp, uint2* __restrict__ esn) {
    int e = blockIdx.x * 256 + threadIdx.x;
    if (e >= N_EDGES) return;
    int d = dst[e];
    int pos = atomicAdd(&fillp[d * 16], 1);
    if (pos < MAXDEG)
        esn[(size_t)d * MAXDEG + pos] = make_uint2((unsigned)src[e], __float_as_uint(ew[e]));
}

// ---------------- per-node: weighted degree from CSR -> dinv ----------------
__global__ void k_node(const uint2* __restrict__ esn, const int* __restrict__ fillp,
                       float* __restrict__ dinv) {
    int n = blockIdx.x * 256 + threadIdx.x;
    if (n >= N_NODES) return;
    int c = min(fillp[n * 16], MAXDEG);
    float s = 1.0f;                           // self-loop weight
    for (int i = 0; i < c; ++i) s += __uint_as_float(esn[(size_t)n * MAXDEG + i].y);
    dinv[n] = rsqrtf(s);
}

// ---------------- MFMA GEMM: C[n][128] = A'[n][128] @ W + bias ----------------
// AMODE 0: A = raw fp32 (x, layer 0). AMODE 1: A = fp32 agg, fused BN+relu (layers 1,2).
template <int AMODE>
__global__ __launch_bounds__(256) void k_gemm_mfma(const float* __restrict__ A,
                                                   const float* __restrict__ mean,
                                                   const float* __restrict__ rstd,
                                                   const __bf16* __restrict__ WT,   // [n][k]
                                                   const float* __restrict__ bias,
                                                   __bf16* __restrict__ C, int nrows) {
    __shared__ __bf16 As[64 * PADK];
    __shared__ __bf16 Ws[128 * PADK];
    int t = threadIdx.x;
    int rowBase = blockIdx.x * 64;
    const uint4* WTg = (const uint4*)WT;
    for (int i = t; i < 2048; i += 256) {       // 128 n-rows x 16 chunks of 8 bf16
        int n = i >> 4, k8 = i & 15;
        *(uint4*)&Ws[n * PADK + k8 * 8] = WTg[i];
    }
    const float4* A4 = (const float4*)A;
    const float4* M4 = (const float4*)mean;
    const float4* R4 = (const float4*)rstd;
    for (int i = t; i < 1024; i += 256) {       // 64 rows x 16 chunks of 8 bf16
        int r = i >> 4, k8 = i & 15;
        int gr = rowBase + r;
        float4 a0 = make_float4(0.f, 0.f, 0.f, 0.f), a1 = a0;
        if (gr < nrows) {
            a0 = A4[(size_t)gr * 32 + k8 * 2];
            a1 = A4[(size_t)gr * 32 + k8 * 2 + 1];
        }
        if (AMODE == 1) {
            float4 m0 = M4[k8 * 2], m1 = M4[k8 * 2 + 1];
            float4 r0 = R4[k8 * 2], r1 = R4[k8 * 2 + 1];
            a0.x = fmaxf((a0.x - m0.x) * r0.x, 0.f); a0.y = fmaxf((a0.y - m0.y) * r0.y, 0.f);
            a0.z = fmaxf((a0.z - m0.z) * r0.z, 0.f); a0.w = fmaxf((a0.w - m0.w) * r0.w, 0.f);
            a1.x = fmaxf((a1.x - m1.x) * r1.x, 0.f); a1.y = fmaxf((a1.y - m1.y) * r1.y, 0.f);
            a1.z = fmaxf((a1.z - m1.z) * r1.z, 0.f); a1.w = fmaxf((a1.w - m1.w) * r1.w, 0.f);
        }
        bf16_8 o = { (__bf16)a0.x, (__bf16)a0.y, (__bf16)a0.z, (__bf16)a0.w,
                     (__bf16)a1.x, (__bf16)a1.y, (__bf16)a1.z, (__bf16)a1.w };
        *(bf16_8*)&As[r * PADK + k8 * 8] = o;
    }
    __syncthreads();
    int wave = t >> 6, lane = t & 63, quad = lane >> 4, m = lane & 15;
    int ar = wave * 16 + m;
    f32_4 acc[8];
#pragma unroll
    for (int i = 0; i < 8; ++i) acc[i] = (f32_4){0.f, 0.f, 0.f, 0.f};
#pragma unroll
    for (int kk = 0; kk < 4; ++kk) {
        bf16_8 a = *(const bf16_8*)&As[ar * PADK + kk * 32 + quad * 8];
#pragma unroll
        for (int n0 = 0; n0 < 8; ++n0) {
            bf16_8 b = *(const bf16_8*)&Ws[(n0 * 16 + m) * PADK + kk * 32 + quad * 8];
            acc[n0] = __builtin_amdgcn_mfma_f32_16x16x32_bf16(a, b, acc[n0], 0, 0, 0);
        }
    }
    __syncthreads();
    // bounce C through LDS (reuse As) for coalesced 16B stores
#pragma unroll
    for (int n0 = 0; n0 < 8; ++n0) {
        int col = n0 * 16 + m;
        float bi = bias[col];
#pragma unroll
        for (int r = 0; r < 4; ++r) {
            int rr = wave * 16 + quad * 4 + r;
            As[rr * PADK + col] = (__bf16)(acc[n0][r] + bi);
        }
    }
    __syncthreads();
    uint4* Cg = (uint4*)C;
    for (int i = t; i < 1024; i += 256) {
        int r = i >> 4, k8 = i & 15;
        int gr = rowBase + r;
        if (gr < nrows) Cg[(size_t)gr * 16 + k8] = *(const uint4*)&As[r * PADK + k8 * 8];
    }
}

// ---------------- edge aggregation + fused BN stats + fused bnfinal (last block) ----------------
__global__ __launch_bounds__(256) void k_agg(const __bf16* __restrict__ hwb,
                                             const uint2* __restrict__ esn,
                                             const int* __restrict__ fillp,
                                             const float* __restrict__ dinv,
                                             float* __restrict__ agg,
                                             float* __restrict__ colpart,
                                             float* __restrict__ mean,
                                             float* __restrict__ rstd,
                                             int* __restrict__ done) {
    __shared__ float red1[4 * 128], red2[4 * 128];
    __shared__ int lastflag;
    int t = threadIdx.x;
    int n = (blockIdx.x * 256 + t) >> 6;
    int lane = t & 63, wave = t >> 6;
    float2 acc = make_float2(0.f, 0.f);
    const unsigned int* hw32 = (const unsigned int*)hwb;
    if (n < N_NODES) {
        float dvn = dinv[n];
        float2 sv = bf2f2(hw32[(size_t)n * 64 + lane]);
        acc.x = sv.x * dvn * dvn; acc.y = sv.y * dvn * dvn;   // self-loop term
        int num = min(fillp[n * 16], MAXDEG);
        int s_l = 0; float w_l = 0.f;
        if (lane < num) {
            uint2 e = esn[(size_t)n * MAXDEG + lane];
            s_l = (int)e.x;
            w_l = dinv[s_l] * __uint_as_float(e.y) * dvn;     // dinv gather: 200KB, L2-resident
        }
        int i = 0;
        for (; i + 8 <= num; i += 8) {
            int ss[8]; float ww[8]; unsigned uu[8];
#pragma unroll
            for (int j = 0; j < 8; ++j) { ss[j] = __shfl(s_l, i + j); ww[j] = __shfl(w_l, i + j); }
#pragma unroll
            for (int j = 0; j < 8; ++j) uu[j] = hw32[(size_t)ss[j] * 64 + lane];
#pragma unroll
            for (int j = 0; j < 8; ++j) {
                float2 f = bf2f2(uu[j]);
                acc.x += f.x * ww[j]; acc.y += f.y * ww[j];
            }
        }
        for (; i < num; ++i) {
            int s = __shfl(s_l, i);
            float w = __shfl(w_l, i);
            float2 f = bf2f2(hw32[(size_t)s * 64 + lane]);
            acc.x += f.x * w; acc.y += f.y * w;
        }
        ((float2*)agg)[(size_t)n * 64 + lane] = acc;   // fp32: BN cancellation needs full precision
    }
    // per-block BN stats, tree reduce; invalid threads contribute 0
    *(float2*)&red1[wave * 128 + 2 * lane] = acc;
    *(float2*)&red2[wave * 128 + 2 * lane] = make_float2(acc.x * acc.x, acc.y * acc.y);
    __syncthreads();
    if (t < 128) {
        float s = red1[t] + red1[128 + t] + red1[256 + t] + red1[384 + t];
        float q = red2[t] + red2[128 + t] + red2[256 + t] + red2[384 + t];
        int c = blockIdx.x & (NCOPY - 1);
        unsafeAtomicAdd(&colpart[c * 128 + t], s);
        unsafeAtomicAdd(&colpart[NCOPY * 128 + c * 128 + t], q);
    }
    // ---- fused bnfinal: last block to finish reduces colpart -> mean/rstd ----
    __threadfence();
    if (t == 0) {
        int tk = atomicAdd(done, 1);
        lastflag = (tk == (int)gridDim.x - 1) ? 1 : 0;
    }
    __syncthreads();
    if (lastflag) {
        if (t < 128) {
            float s = 0.f, q = 0.f;
            for (int c = 0; c < NCOPY; ++c) {
                s += __hip_atomic_load(&colpart[c * 128 + t], __ATOMIC_RELAXED,
                                       __HIP_MEMORY_SCOPE_AGENT);
                q += __hip_atomic_load(&colpart[NCOPY * 128 + c * 128 + t], __ATOMIC_RELAXED,
                                       __HIP_MEMORY_SCOPE_AGENT);
                __hip_atomic_store(&colpart[c * 128 + t], 0.f, __ATOMIC_RELAXED,
                                   __HIP_MEMORY_SCOPE_AGENT);
                __hip_atomic_store(&colpart[NCOPY * 128 + c * 128 + t], 0.f, __ATOMIC_RELAXED,
                                   __HIP_MEMORY_SCOPE_AGENT);
            }
            float m = s * (1.0f / N_NODES);
            float v = q * (1.0f / N_NODES) - m * m;
            mean[t] = m;
            rstd[t] = rsqrtf(v + 1e-5f);
        }
        if (t == 0) *done = 0;   // ready for next layer
    }
}

// ---------------- scoring prep: h_cn from fp32 agg + BN, then c0 = h_cn @ W1b + lin1_b ----------
__global__ void k_prep(const float* __restrict__ agg, const float* __restrict__ mean,
                       const float* __restrict__ rstd, const int* __restrict__ cid,
                       const float* __restrict__ lin1w, const float* __restrict__ lin1b,
                       float* c0) {
    __shared__ float xc[128];
    int t = threadIdx.x;  // 128
    int cn = cid[0];
    float a = agg[(size_t)cn * 128 + t];
    xc[t] = fmaxf((a - mean[t]) * rstd[t], 0.f);
    __syncthreads();
    float acc = lin1b[t];
    for (int k = 0; k < 128; ++k)
        acc += xc[k] * lin1w[(size_t)(128 + k) * 128 + t];
    c0[t] = acc;
}

// ---------------- scoring: fused BN+relu staging (writes fp32 h) + MFMA + relu + dot(lin2) ------
__global__ __launch_bounds__(256) void k_score_mfma(const float* __restrict__ agg,
                                                    const float* __restrict__ mean,
                                                    const float* __restrict__ rstd,
                                                    const __bf16* __restrict__ WT,
                                                    const float* __restrict__ c0,
                                                    const float* __restrict__ svec,
                                                    const float* __restrict__ ecn,
                                                    const float* __restrict__ lin2w,
                                                    const float* __restrict__ lin2b,
                                                    float* __restrict__ scores,
                                                    float* __restrict__ hout,
                                                    int nrows) {
    __shared__ __bf16 As[64 * PADK];
    __shared__ __bf16 Ws[128 * PADK];
    __shared__ float c0s[128], svs[128], l2s[128];
    int t = threadIdx.x;
    int rowBase = blockIdx.x * 64;
    const uint4* WTg = (const uint4*)WT;
    for (int i = t; i < 2048; i += 256) {
        int n = i >> 4, k8 = i & 15;
        *(uint4*)&Ws[n * PADK + k8 * 8] = WTg[i];
    }
    const float4* A4 = (const float4*)agg;
    const float4* M4 = (const float4*)mean;
    const float4* R4 = (const float4*)rstd;
    float4* H4 = (float4*)hout;
    for (int i = t; i < 1024; i += 256) {
        int r = i >> 4, k8 = i & 15;
        int gr = rowBase + r;
        float4 a0 = make_float4(0.f, 0.f, 0.f, 0.f), a1 = a0;
        if (gr < nrows) {
            a0 = A4[(size_t)gr * 32 + k8 * 2];
            a1 = A4[(size_t)gr * 32 + k8 * 2 + 1];
        }
        float4 m0 = M4[k8 * 2], m1 = M4[k8 * 2 + 1];
        float4 r0 = R4[k8 * 2], r1 = R4[k8 * 2 + 1];
        float4 f0, f1;
        f0.x = fmaxf((a0.x - m0.x) * r0.x, 0.f); f0.y = fmaxf((a0.y - m0.y) * r0.y, 0.f);
        f0.z = fmaxf((a0.z - m0.z) * r0.z, 0.f); f0.w = fmaxf((a0.w - m0.w) * r0.w, 0.f);
        f1.x = fmaxf((a1.x - m1.x) * r1.x, 0.f); f1.y = fmaxf((a1.y - m1.y) * r1.y, 0.f);
        f1.z = fmaxf((a1.z - m1.z) * r1.z, 0.f); f1.w = fmaxf((a1.w - m1.w) * r1.w, 0.f);
        if (gr < nrows) {
            H4[(size_t)gr * 32 + k8 * 2] = f0;       // fp32 h output (d_out)
            H4[(size_t)gr * 32 + k8 * 2 + 1] = f1;
        }
        bf16_8 o = { (__bf16)f0.x, (__bf16)f0.y, (__bf16)f0.z, (__bf16)f0.w,
                     (__bf16)f1.x, (__bf16)f1.y, (__bf16)f1.z, (__bf16)f1.w };
        *(bf16_8*)&As[r * PADK + k8 * 8] = o;
    }
    if (t < 128) { c0s[t] = c0[t]; svs[t] = svec[t]; l2s[t] = lin2w[t]; }
    __syncthreads();
    int wave = t >> 6, lane = t & 63, quad = lane >> 4, m = lane & 15;
    int ar = wave * 16 + m;
    f32_4 acc[8];
#pragma unroll
    for (int i = 0; i < 8; ++i) acc[i] = (f32_4){0.f, 0.f, 0.f, 0.f};
#pragma unroll
    for (int kk = 0; kk < 4; ++kk) {
        bf16_8 a = *(const bf16_8*)&As[ar * PADK + kk * 32 + quad * 8];
#pragma unroll
        for (int n0 = 0; n0 < 8; ++n0) {
            bf16_8 b = *(const bf16_8*)&Ws[(n0 * 16 + m) * PADK + kk * 32 + quad * 8];
            acc[n0] = __builtin_amdgcn_mfma_f32_16x16x32_bf16(a, b, acc[n0], 0, 0, 0);
        }
    }
    float l2b = lin2b[0];
#pragma unroll
    for (int r = 0; r < 4; ++r) {
        int row = rowBase + wave * 16 + quad * 4 + r;
        float e = (row < nrows) ? ecn[row] : 0.f;
        float partial = 0.f;
#pragma unroll
        for (int n0 = 0; n0 < 8; ++n0) {
            int col = n0 * 16 + m;
            float v = acc[n0][r] + c0s[col] + e * svs[col];
            partial += fmaxf(v, 0.f) * l2s[col];
        }
        partial += __shfl_xor(partial, 8, 16);
        partial += __shfl_xor(partial, 4, 16);
        partial += __shfl_xor(partial, 2, 16);
        partial += __shfl_xor(partial, 1, 16);
        if (m == 0 && row < nrows) scores[row] = partial + l2b;
    }
}

// ---------------- partition pooling ----------------
__global__ void k_partition(const float* __restrict__ scores, const float* __restrict__ part,
                            float* out) {
    __shared__ float red[256];
    int t = threadIdx.x;
    int p = t & 31, rg = t >> 5;  // 8 row groups
    float acc = 0.f;
    for (int r = blockIdx.x * 8 + rg; r < N_NODES; r += gridDim.x * 8)
        acc += scores[r] * part[(size_t)r * 32 + p];
    red[t] = acc;
    __syncthreads();
    if (t < 32) {
        float s = 0.f;
        for (int i = 0; i < 8; ++i) s += red[i * 32 + t];
        unsafeAtomicAdd(&out[t], s);
    }
}

// ---------------- host ----------------
extern "C" void kernel_launch(void* const* d_in, const int* in_sizes, int n_in,
                              void* d_out, int out_size, void* d_ws, size_t ws_size,
                              hipStream_t stream) {
    const float* x        = (const float*)d_in[0];
    const int*   eidx     = (const int*)d_in[1];
    const float* ew       = (const float*)d_in[2];
    const float* parts    = (const float*)d_in[3];
    // d_in[4] = node_weights (unused by reference)
    const float* ecn      = (const float*)d_in[5];
    const float* conv_w   = (const float*)d_in[6];
    const float* conv_b   = (const float*)d_in[7];
    const float* lin1_w   = (const float*)d_in[8];
    const float* lin1_b   = (const float*)d_in[9];
    const float* lin2_w   = (const float*)d_in[10];
    const float* lin2_b   = (const float*)d_in[11];
    const int*   cid      = (const int*)d_in[12];

    const int* src = eidx;
    const int* dst = eidx + N_EDGES;

    // workspace layout
    char* p = (char*)d_ws;
    auto alloc = [&](size_t bytes) { char* r = p; p += (bytes + 255) & ~size_t(255); return r; };
    int*    fillp   = (int*)alloc((size_t)N_NODES * 16 * 4);          // 3.2 MB, 1 counter / 64B line
    uint2*  esn     = (uint2*)alloc((size_t)N_NODES * MAXDEG * 8);    // 25.6 MB direct-slot CSR
    float*  dinv    = (float*)alloc(NP * 4);
    float*  scores  = (float*)alloc(NP * 4);
    float*  colpart = (float*)alloc(2 * NCOPY * 128 * 4);
    float*  mean    = (float*)alloc(128 * 4);
    float*  rstd    = (float*)alloc(128 * 4);
    float*  c0      = (float*)alloc(128 * 4);
    float*  svec    = (float*)alloc(128 * 4);
    int*    done    = (int*)alloc(256);
    __bf16* WT      = (__bf16*)alloc(4 * 128 * 128 * 2);
    __bf16* hwb     = (__bf16*)alloc((size_t)N_NODES * 128 * 2);
    float*  agg     = (float*)alloc((size_t)N_NODES * 128 * 4);

    float* out_head = (float*)d_out;          // partition_scores [32]
    float* hbuf     = (float*)d_out + 32;     // final h [N,128] fp32

    const int NB = (NP + 255) / 256;          // 196
    const int GB = (N_NODES + 63) / 64;       // 782 mfma-gemm blocks
    const int AB = (N_NODES * 64 + 255) / 256;// 12500 agg blocks (1 wave/node)

    k_init_wprep<<<EB + WPB + 1, 256, 0, stream>>>(fillp, colpart, out_head, done,
                                                   conv_w, lin1_w, WT, svec);
    k_fillover<<<EB, 256, 0, stream>>>(src, dst, ew, fillp, esn);
    k_node<<<NB, 256, 0, stream>>>(esn, fillp, dinv);

    for (int l = 0; l < 3; ++l) {
        if (l == 0)
            k_gemm_mfma<0><<<GB, 256, 0, stream>>>(x, mean, rstd, WT, conv_b, hwb, N_NODES);
        else
            k_gemm_mfma<1><<<GB, 256, 0, stream>>>(agg, mean, rstd, WT + (size_t)l * 16384,
                                                   conv_b + (size_t)l * 128, hwb, N_NODES);
        k_agg<<<AB, 256, 0, stream>>>(hwb, esn, fillp, dinv, agg, colpart, mean, rstd, done);
    }

    k_prep<<<1, 128, 0, stream>>>(agg, mean, rstd, cid, lin1_w, lin1_b, c0);
    k_score_mfma<<<GB, 256, 0, stream>>>(agg, mean, rstd, WT + (size_t)3 * 16384, c0, svec,
                                         ecn, lin2_w, lin2_b, scores, hbuf, N_NODES);
    k_partition<<<256, 256, 0, stream>>>(scores, parts, out_head);
}

// Round 8
// 354.161 us; speedup vs baseline: 9.6477x; 9.6477x over previous
//
#include <hip/hip_runtime.h>

#define N_NODES 50000
#define N_EDGES 800000
#define NP 50048          // N padded to multiple of 64
#define MAXDEG 64         // CSR slots per node; Poisson(16) -> P(deg>=64) ~ 1e-19
#define PADK 136          // 128 + 8 bf16 pad
#define NCOPY 64          // BN-stat replication
#define EB 3125           // edge blocks (3125*256 == 800000)
#define WPB 512           // wprep blocks appended to k_init grid

typedef __bf16 bf16_8 __attribute__((ext_vector_type(8)));
typedef float  f32_4  __attribute__((ext_vector_type(4)));

__device__ inline float2 bf2f2(unsigned int u) {
    union { unsigned int i; float f; } a, b;
    a.i = u << 16;            // low short  = element 0
    b.i = u & 0xffff0000u;    // high short = element 1
    return make_float2(a.f, b.f);
}

// ---------------- init + weight transpose + svec, one launch ----------------
__global__ void k_init_wprep(int* __restrict__ fillp, float* __restrict__ colpart,
                             float* __restrict__ out_head,
                             const float* __restrict__ conv_w, const float* __restrict__ lin1_w,
                             __bf16* __restrict__ WT, float* __restrict__ svec) {
    int b = blockIdx.x;
    if (b < EB) {
        int i = b * 256 + threadIdx.x;       // covers exactly N_NODES*16 = 800000
        fillp[i] = 0;
        if (i < 2 * NCOPY * 128) colpart[i] = 0.f;
        if (i < 32) out_head[i] = 0.f;
    } else if (b < EB + WPB) {
        int b2 = b - EB;                     // 0..511
        int mat = b2 >> 7, n = b2 & 127, k = threadIdx.x;
        if (k < 128) {
            const float* srcm = (mat < 3) ? (conv_w + (size_t)mat * 16384) : lin1_w;
            WT[((size_t)mat * 128 + n) * 128 + k] = (__bf16)srcm[(size_t)k * 128 + n];
        }
    } else {
        int j = threadIdx.x;                 // svec = colsum of lin1_w rows 256..511
        if (j < 128) {
            float s = 0.f;
            for (int k = 256; k < 512; ++k) s += lin1_w[(size_t)k * 128 + j];
            svec[j] = s;
        }
    }
}

// ---------------- direct-slot CSR fill: ONE atomic per edge ----------------
__global__ void k_fillover(const int* __restrict__ src, const int* __restrict__ dst,
                           const float* __restrict__ ew,
                           int* __restrict__ fillp, uint2* __restrict__ esn) {
    int e = blockIdx.x * 256 + threadIdx.x;
    if (e >= N_EDGES) return;
    int d = dst[e];
    int pos = atomicAdd(&fillp[d * 16], 1);
    if (pos < MAXDEG)
        esn[(size_t)d * MAXDEG + pos] = make_uint2((unsigned)src[e], __float_as_uint(ew[e]));
}

// ---------------- per-node: weighted degree from CSR -> dinv ----------------
__global__ void k_node(const uint2* __restrict__ esn, const int* __restrict__ fillp,
                       float* __restrict__ dinv) {
    int n = blockIdx.x * 256 + threadIdx.x;
    if (n >= N_NODES) return;
    int c = min(fillp[n * 16], MAXDEG);
    float s = 1.0f;                           // self-loop weight
    for (int i = 0; i < c; ++i) s += __uint_as_float(esn[(size_t)n * MAXDEG + i].y);
    dinv[n] = rsqrtf(s);
}

// ---------------- MFMA GEMM: C[n][128] = A'[n][128] @ W + bias ----------------
// AMODE 0: A = raw fp32 (x, layer 0). AMODE 1: A = fp32 agg, fused BN+relu (layers 1,2).
template <int AMODE>
__global__ __launch_bounds__(256) void k_gemm_mfma(const float* __restrict__ A,
                                                   const float* __restrict__ mean,
                                                   const float* __restrict__ rstd,
                                                   const __bf16* __restrict__ WT,   // [n][k]
                                                   const float* __restrict__ bias,
                                                   __bf16* __restrict__ C, int nrows) {
    __shared__ __bf16 As[64 * PADK];
    __shared__ __bf16 Ws[128 * PADK];
    int t = threadIdx.x;
    int rowBase = blockIdx.x * 64;
    const uint4* WTg = (const uint4*)WT;
    for (int i = t; i < 2048; i += 256) {       // 128 n-rows x 16 chunks of 8 bf16
        int n = i >> 4, k8 = i & 15;
        *(uint4*)&Ws[n * PADK + k8 * 8] = WTg[i];
    }
    const float4* A4 = (const float4*)A;
    const float4* M4 = (const float4*)mean;
    const float4* R4 = (const float4*)rstd;
    for (int i = t; i < 1024; i += 256) {       // 64 rows x 16 chunks of 8 bf16
        int r = i >> 4, k8 = i & 15;
        int gr = rowBase + r;
        float4 a0 = make_float4(0.f, 0.f, 0.f, 0.f), a1 = a0;
        if (gr < nrows) {
            a0 = A4[(size_t)gr * 32 + k8 * 2];
            a1 = A4[(size_t)gr * 32 + k8 * 2 + 1];
        }
        if (AMODE == 1) {
            float4 m0 = M4[k8 * 2], m1 = M4[k8 * 2 + 1];
            float4 r0 = R4[k8 * 2], r1 = R4[k8 * 2 + 1];
            a0.x = fmaxf((a0.x - m0.x) * r0.x, 0.f); a0.y = fmaxf((a0.y - m0.y) * r0.y, 0.f);
            a0.z = fmaxf((a0.z - m0.z) * r0.z, 0.f); a0.w = fmaxf((a0.w - m0.w) * r0.w, 0.f);
            a1.x = fmaxf((a1.x - m1.x) * r1.x, 0.f); a1.y = fmaxf((a1.y - m1.y) * r1.y, 0.f);
            a1.z = fmaxf((a1.z - m1.z) * r1.z, 0.f); a1.w = fmaxf((a1.w - m1.w) * r1.w, 0.f);
        }
        bf16_8 o = { (__bf16)a0.x, (__bf16)a0.y, (__bf16)a0.z, (__bf16)a0.w,
                     (__bf16)a1.x, (__bf16)a1.y, (__bf16)a1.z, (__bf16)a1.w };
        *(bf16_8*)&As[r * PADK + k8 * 8] = o;
    }
    __syncthreads();
    int wave = t >> 6, lane = t & 63, quad = lane >> 4, m = lane & 15;
    int ar = wave * 16 + m;
    f32_4 acc[8];
#pragma unroll
    for (int i = 0; i < 8; ++i) acc[i] = (f32_4){0.f, 0.f, 0.f, 0.f};
#pragma unroll
    for (int kk = 0; kk < 4; ++kk) {
        bf16_8 a = *(const bf16_8*)&As[ar * PADK + kk * 32 + quad * 8];
#pragma unroll
        for (int n0 = 0; n0 < 8; ++n0) {
            bf16_8 b = *(const bf16_8*)&Ws[(n0 * 16 + m) * PADK + kk * 32 + quad * 8];
            acc[n0] = __builtin_amdgcn_mfma_f32_16x16x32_bf16(a, b, acc[n0], 0, 0, 0);
        }
    }
    __syncthreads();
    // bounce C through LDS (reuse As) for coalesced 16B stores
#pragma unroll
    for (int n0 = 0; n0 < 8; ++n0) {
        int col = n0 * 16 + m;
        float bi = bias[col];
#pragma unroll
        for (int r = 0; r < 4; ++r) {
            int rr = wave * 16 + quad * 4 + r;
            As[rr * PADK + col] = (__bf16)(acc[n0][r] + bi);
        }
    }
    __syncthreads();
    uint4* Cg = (uint4*)C;
    for (int i = t; i < 1024; i += 256) {
        int r = i >> 4, k8 = i & 15;
        int gr = rowBase + r;
        if (gr < nrows) Cg[(size_t)gr * 16 + k8] = *(const uint4*)&As[r * PADK + k8 * 8];
    }
}

// ---------------- edge aggregation + fused BN stats (NO device fence — see R7 post-mortem) -----
__global__ __launch_bounds__(256) void k_agg(const __bf16* __restrict__ hwb,
                                             const uint2* __restrict__ esn,
                                             const int* __restrict__ fillp,
                                             const float* __restrict__ dinv,
                                             float* __restrict__ agg,
                                             float* __restrict__ colpart) {
    __shared__ float red1[4 * 128], red2[4 * 128];
    int t = threadIdx.x;
    int n = (blockIdx.x * 256 + t) >> 6;
    int lane = t & 63, wave = t >> 6;
    float2 acc = make_float2(0.f, 0.f);
    const unsigned int* hw32 = (const unsigned int*)hwb;
    if (n < N_NODES) {
        float dvn = dinv[n];
        float2 sv = bf2f2(hw32[(size_t)n * 64 + lane]);
        acc.x = sv.x * dvn * dvn; acc.y = sv.y * dvn * dvn;   // self-loop term
        int num = min(fillp[n * 16], MAXDEG);
        int s_l = 0; float w_l = 0.f;
        if (lane < num) {
            uint2 e = esn[(size_t)n * MAXDEG + lane];
            s_l = (int)e.x;
            w_l = dinv[s_l] * __uint_as_float(e.y) * dvn;     // dinv gather: 200KB, L2-resident
        }
        int i = 0;
        for (; i + 8 <= num; i += 8) {
            int ss[8]; float ww[8]; unsigned uu[8];
#pragma unroll
            for (int j = 0; j < 8; ++j) { ss[j] = __shfl(s_l, i + j); ww[j] = __shfl(w_l, i + j); }
#pragma unroll
            for (int j = 0; j < 8; ++j) uu[j] = hw32[(size_t)ss[j] * 64 + lane];
#pragma unroll
            for (int j = 0; j < 8; ++j) {
                float2 f = bf2f2(uu[j]);
                acc.x += f.x * ww[j]; acc.y += f.y * ww[j];
            }
        }
        for (; i < num; ++i) {
            int s = __shfl(s_l, i);
            float w = __shfl(w_l, i);
            float2 f = bf2f2(hw32[(size_t)s * 64 + lane]);
            acc.x += f.x * w; acc.y += f.y * w;
        }
        ((float2*)agg)[(size_t)n * 64 + lane] = acc;   // fp32: BN cancellation needs full precision
    }
    // per-block BN stats, tree reduce; invalid threads contribute 0
    *(float2*)&red1[wave * 128 + 2 * lane] = acc;
    *(float2*)&red2[wave * 128 + 2 * lane] = make_float2(acc.x * acc.x, acc.y * acc.y);
    __syncthreads();
    if (t < 128) {
        float s = red1[t] + red1[128 + t] + red1[256 + t] + red1[384 + t];
        float q = red2[t] + red2[128 + t] + red2[256 + t] + red2[384 + t];
        int c = blockIdx.x & (NCOPY - 1);
        unsafeAtomicAdd(&colpart[c * 128 + t], s);
        unsafeAtomicAdd(&colpart[NCOPY * 128 + c * 128 + t], q);
    }
}

// separate 1-block kernel: launch boundary gives cross-XCD visibility for free
__global__ void k_bnfinal(float* colpart, float* mean, float* rstd) {
    int j = threadIdx.x;  // 128
    float s = 0.f, q = 0.f;
    for (int c = 0; c < NCOPY; ++c) {
        s += colpart[c * 128 + j];
        q += colpart[NCOPY * 128 + c * 128 + j];
        colpart[c * 128 + j] = 0.f;                 // ready for next layer
        colpart[NCOPY * 128 + c * 128 + j] = 0.f;
    }
    float m = s * (1.0f / N_NODES);
    float v = q * (1.0f / N_NODES) - m * m;
    mean[j] = m;
    rstd[j] = rsqrtf(v + 1e-5f);
}

// ---------------- scoring prep: h_cn from fp32 agg + BN, then c0 = h_cn @ W1b + lin1_b ----------
__global__ void k_prep(const float* __restrict__ agg, const float* __restrict__ mean,
                       const float* __restrict__ rstd, const int* __restrict__ cid,
                       const float* __restrict__ lin1w, const float* __restrict__ lin1b,
                       float* c0) {
    __shared__ float xc[128];
    int t = threadIdx.x;  // 128
    int cn = cid[0];
    float a = agg[(size_t)cn * 128 + t];
    xc[t] = fmaxf((a - mean[t]) * rstd[t], 0.f);
    __syncthreads();
    float acc = lin1b[t];
    for (int k = 0; k < 128; ++k)
        acc += xc[k] * lin1w[(size_t)(128 + k) * 128 + t];
    c0[t] = acc;
}

// ---------------- scoring: fused BN+relu staging (writes fp32 h) + MFMA + relu + dot(lin2) ------
__global__ __launch_bounds__(256) void k_score_mfma(const float* __restrict__ agg,
                                                    const float* __restrict__ mean,
                                                    const float* __restrict__ rstd,
                                                    const __bf16* __restrict__ WT,
                                                    const float* __restrict__ c0,
                                                    const float* __restrict__ svec,
                                                    const float* __restrict__ ecn,
                                                    const float* __restrict__ lin2w,
                                                    const float* __restrict__ lin2b,
                                                    float* __restrict__ scores,
                                                    float* __restrict__ hout,
                                                    int nrows) {
    __shared__ __bf16 As[64 * PADK];
    __shared__ __bf16 Ws[128 * PADK];
    __shared__ float c0s[128], svs[128], l2s[128];
    int t = threadIdx.x;
    int rowBase = blockIdx.x * 64;
    const uint4* WTg = (const uint4*)WT;
    for (int i = t; i < 2048; i += 256) {
        int n = i >> 4, k8 = i & 15;
        *(uint4*)&Ws[n * PADK + k8 * 8] = WTg[i];
    }
    const float4* A4 = (const float4*)agg;
    const float4* M4 = (const float4*)mean;
    const float4* R4 = (const float4*)rstd;
    float4* H4 = (float4*)hout;
    for (int i = t; i < 1024; i += 256) {
        int r = i >> 4, k8 = i & 15;
        int gr = rowBase + r;
        float4 a0 = make_float4(0.f, 0.f, 0.f, 0.f), a1 = a0;
        if (gr < nrows) {
            a0 = A4[(size_t)gr * 32 + k8 * 2];
            a1 = A4[(size_t)gr * 32 + k8 * 2 + 1];
        }
        float4 m0 = M4[k8 * 2], m1 = M4[k8 * 2 + 1];
        float4 r0 = R4[k8 * 2], r1 = R4[k8 * 2 + 1];
        float4 f0, f1;
        f0.x = fmaxf((a0.x - m0.x) * r0.x, 0.f); f0.y = fmaxf((a0.y - m0.y) * r0.y, 0.f);
        f0.z = fmaxf((a0.z - m0.z) * r0.z, 0.f); f0.w = fmaxf((a0.w - m0.w) * r0.w, 0.f);
        f1.x = fmaxf((a1.x - m1.x) * r1.x, 0.f); f1.y = fmaxf((a1.y - m1.y) * r1.y, 0.f);
        f1.z = fmaxf((a1.z - m1.z) * r1.z, 0.f); f1.w = fmaxf((a1.w - m1.w) * r1.w, 0.f);
        if (gr < nrows) {
            H4[(size_t)gr * 32 + k8 * 2] = f0;       // fp32 h output (d_out)
            H4[(size_t)gr * 32 + k8 * 2 + 1] = f1;
        }
        bf16_8 o = { (__bf16)f0.x, (__bf16)f0.y, (__bf16)f0.z, (__bf16)f0.w,
                     (__bf16)f1.x, (__bf16)f1.y, (__bf16)f1.z, (__bf16)f1.w };
        *(bf16_8*)&As[r * PADK + k8 * 8] = o;
    }
    if (t < 128) { c0s[t] = c0[t]; svs[t] = svec[t]; l2s[t] = lin2w[t]; }
    __syncthreads();
    int wave = t >> 6, lane = t & 63, quad = lane >> 4, m = lane & 15;
    int ar = wave * 16 + m;
    f32_4 acc[8];
#pragma unroll
    for (int i = 0; i < 8; ++i) acc[i] = (f32_4){0.f, 0.f, 0.f, 0.f};
#pragma unroll
    for (int kk = 0; kk < 4; ++kk) {
        bf16_8 a = *(const bf16_8*)&As[ar * PADK + kk * 32 + quad * 8];
#pragma unroll
        for (int n0 = 0; n0 < 8; ++n0) {
            bf16_8 b = *(const bf16_8*)&Ws[(n0 * 16 + m) * PADK + kk * 32 + quad * 8];
            acc[n0] = __builtin_amdgcn_mfma_f32_16x16x32_bf16(a, b, acc[n0], 0, 0, 0);
        }
    }
    float l2b = lin2b[0];
#pragma unroll
    for (int r = 0; r < 4; ++r) {
        int row = rowBase + wave * 16 + quad * 4 + r;
        float e = (row < nrows) ? ecn[row] : 0.f;
        float partial = 0.f;
#pragma unroll
        for (int n0 = 0; n0 < 8; ++n0) {
            int col = n0 * 16 + m;
            float v = acc[n0][r] + c0s[col] + e * svs[col];
            partial += fmaxf(v, 0.f) * l2s[col];
        }
        partial += __shfl_xor(partial, 8, 16);
        partial += __shfl_xor(partial, 4, 16);
        partial += __shfl_xor(partial, 2, 16);
        partial += __shfl_xor(partial, 1, 16);
        if (m == 0 && row < nrows) scores[row] = partial + l2b;
    }
}

// ---------------- partition pooling ----------------
__global__ void k_partition(const float* __restrict__ scores, const float* __restrict__ part,
                            float* out) {
    __shared__ float red[256];
    int t = threadIdx.x;
    int p = t & 31, rg = t >> 5;  // 8 row groups
    float acc = 0.f;
    for (int r = blockIdx.x * 8 + rg; r < N_NODES; r += gridDim.x * 8)
        acc += scores[r] * part[(size_t)r * 32 + p];
    red[t] = acc;
    __syncthreads();
    if (t < 32) {
        float s = 0.f;
        for (int i = 0; i < 8; ++i) s += red[i * 32 + t];
        unsafeAtomicAdd(&out[t], s);
    }
}

// ---------------- host ----------------
extern "C" void kernel_launch(void* const* d_in, const int* in_sizes, int n_in,
                              void* d_out, int out_size, void* d_ws, size_t ws_size,
                              hipStream_t stream) {
    const float* x        = (const float*)d_in[0];
    const int*   eidx     = (const int*)d_in[1];
    const float* ew       = (const float*)d_in[2];
    const float* parts    = (const float*)d_in[3];
    // d_in[4] = node_weights (unused by reference)
    const float* ecn      = (const float*)d_in[5];
    const float* conv_w   = (const float*)d_in[6];
    const float* conv_b   = (const float*)d_in[7];
    const float* lin1_w   = (const float*)d_in[8];
    const float* lin1_b   = (const float*)d_in[9];
    const float* lin2_w   = (const float*)d_in[10];
    const float* lin2_b   = (const float*)d_in[11];
    const int*   cid      = (const int*)d_in[12];

    const int* src = eidx;
    const int* dst = eidx + N_EDGES;

    // workspace layout
    char* p = (char*)d_ws;
    auto alloc = [&](size_t bytes) { char* r = p; p += (bytes + 255) & ~size_t(255); return r; };
    int*    fillp   = (int*)alloc((size_t)N_NODES * 16 * 4);          // 3.2 MB, 1 counter / 64B line
    uint2*  esn     = (uint2*)alloc((size_t)N_NODES * MAXDEG * 8);    // 25.6 MB direct-slot CSR
    float*  dinv    = (float*)alloc(NP * 4);
    float*  scores  = (float*)alloc(NP * 4);
    float*  colpart = (float*)alloc(2 * NCOPY * 128 * 4);
    float*  mean    = (float*)alloc(128 * 4);
    float*  rstd    = (float*)alloc(128 * 4);
    float*  c0      = (float*)alloc(128 * 4);
    float*  svec    = (float*)alloc(128 * 4);
    __bf16* WT      = (__bf16*)alloc(4 * 128 * 128 * 2);
    __bf16* hwb     = (__bf16*)alloc((size_t)N_NODES * 128 * 2);
    float*  agg     = (float*)alloc((size_t)N_NODES * 128 * 4);

    float* out_head = (float*)d_out;          // partition_scores [32]
    float* hbuf     = (float*)d_out + 32;     // final h [N,128] fp32

    const int NB = (NP + 255) / 256;          // 196
    const int GB = (N_NODES + 63) / 64;       // 782 mfma-gemm blocks
    const int AB = (N_NODES * 64 + 255) / 256;// 12500 agg blocks (1 wave/node)

    k_init_wprep<<<EB + WPB + 1, 256, 0, stream>>>(fillp, colpart, out_head,
                                                   conv_w, lin1_w, WT, svec);
    k_fillover<<<EB, 256, 0, stream>>>(src, dst, ew, fillp, esn);
    k_node<<<NB, 256, 0, stream>>>(esn, fillp, dinv);

    for (int l = 0; l < 3; ++l) {
        if (l == 0)
            k_gemm_mfma<0><<<GB, 256, 0, stream>>>(x, mean, rstd, WT, conv_b, hwb, N_NODES);
        else
            k_gemm_mfma<1><<<GB, 256, 0, stream>>>(agg, mean, rstd, WT + (size_t)l * 16384,
                                                   conv_b + (size_t)l * 128, hwb, N_NODES);
        k_agg<<<AB, 256, 0, stream>>>(hwb, esn, fillp, dinv, agg, colpart);
        k_bnfinal<<<1, 128, 0, stream>>>(colpart, mean, rstd);
    }

    k_prep<<<1, 128, 0, stream>>>(agg, mean, rstd, cid, lin1_w, lin1_b, c0);
    k_score_mfma<<<GB, 256, 0, stream>>>(agg, mean, rstd, WT + (size_t)3 * 16384, c0, svec,
                                         ecn, lin2_w, lin2_b, scores, hbuf, N_NODES);
    k_partition<<<256, 256, 0, stream>>>(scores, parts, out_head);
}